// Round 12
// baseline (145.482 us; speedup 1.0000x reference)
//
#include <hip/hip_runtime.h>
#include <hip/hip_bf16.h>
#include <math.h>

// Problem constants: B=2, S=2048, D=1024, HQ=16, HKV=8, DK=DV=64
typedef __attribute__((ext_vector_type(8))) short bf16x8;   // 8 bf16 (4 VGPRs)
typedef __attribute__((ext_vector_type(4))) float f32x4;

// ws layout (byte offsets)
#define OFF_XB  0ull             // bf16 [4096][1024]   8 MB
#define OFF_WT  (8ull<<20)       // bf16 [2048][1024]   4 MB  ([Wq|Wk|Wv]^T)
#define OFF_WO  (12ull<<20)      // bf16 [1024][1024]   2 MB  (Wo^T)
#define OFF_QB  (14ull<<20)      // bf16 [2][16][2048][64]  8 MB (RoPE'd, scaled 1/8*log2e)
#define OFF_KB  (22ull<<20)      // bf16 [2][8][2048][64]   4 MB (RoPE'd)
#define OFF_VT  (26ull<<20)      // bf16 [2][8][64][2048]   4 MB (V^T)
#define OFF_AO  (30ull<<20)      // bf16 [4096][1024]   8 MB (attn out)
#define OFF_MB  (38ull<<20)      // f32  [2][2048] mask bias (0 / -1e30)

#define QSCALE 0.18033688056680276f   // 0.125 * log2(e): softmax in exp2 domain

__device__ inline unsigned pack_bf162(float a, float b) {
    __hip_bfloat162 t = __float22bfloat162_rn(make_float2(a, b));  // a -> low 16 bits
    return *(unsigned*)&t;
}

__device__ inline float exp2_fast(float x) {
    float r;
    asm("v_exp_f32 %0, %1" : "=v"(r) : "v"(x));
    return r;
}

__device__ inline void gload16(const void* g, void* l) {
    __builtin_amdgcn_global_load_lds(
        (const __attribute__((address_space(1))) void*)g,
        (__attribute__((address_space(3))) void*)l, 16, 0, 0);
}

// ---------------- prep: x->bf16, W transposes->bf16, mask canon ----------------
__launch_bounds__(256)
__global__ void prep_kernel(const float* __restrict__ x,
                            const float* __restrict__ Wq, const float* __restrict__ Wk,
                            const float* __restrict__ Wv, const float* __restrict__ Wo,
                            const void* __restrict__ mraw,
                            __hip_bfloat16* __restrict__ XB,
                            __hip_bfloat16* __restrict__ WT,
                            __hip_bfloat16* __restrict__ WoT,
                            float* __restrict__ mbias) {
    __shared__ float T[32][33];
    __shared__ int bad01, badf;
    const int tid = threadIdx.x;
    const int bid = blockIdx.x;
    if (bid < 1024) {                       // x -> bf16
        const int base = bid * 4096;
#pragma unroll
        for (int i = 0; i < 4; ++i) {
            const int e = base + (i * 256 + tid) * 4;
            const float4 v = *(const float4*)&x[e];
            uint2 pk;
            pk.x = pack_bf162(v.x, v.y);
            pk.y = pack_bf162(v.z, v.w);
            *(uint2*)&XB[e] = pk;
        }
    } else if (bid < 4096) {                // W transposes
        const float* src; int ldn, nbase; __hip_bfloat16* dst; int n0, k0;
        if (bid < 3072) {
            const int tb = bid - 1024;
            const int kt = tb >> 6, nt = tb & 63;
            n0 = nt * 32; k0 = kt * 32; dst = WT;
            if (n0 < 1024)      { src = Wq; ldn = 1024; nbase = n0; }
            else if (n0 < 1536) { src = Wk; ldn = 512;  nbase = n0 - 1024; }
            else                { src = Wv; ldn = 512;  nbase = n0 - 1536; }
        } else {
            const int tb = bid - 3072;
            const int kt = tb >> 5, nt = tb & 31;
            n0 = nt * 32; k0 = kt * 32; dst = WoT;
            src = Wo; ldn = 1024; nbase = n0;
        }
        const int c = tid & 31, r0 = tid >> 5;
#pragma unroll
        for (int i = 0; i < 4; ++i)
            T[r0 + 8 * i][c] = src[(size_t)(k0 + r0 + 8 * i) * ldn + nbase + c];
        __syncthreads();
#pragma unroll
        for (int i = 0; i < 4; ++i) {
            const int nn = r0 + 8 * i;
            dst[(size_t)(n0 + nn) * 1024 + k0 + c] = __float2bfloat16(T[c][nn]);
        }
    } else {                                // mask canonicalization
        if (tid == 0) { bad01 = 0; badf = 0; }
        __syncthreads();
        const unsigned* w = (const unsigned*)mraw;
#pragma unroll
        for (int i = 0; i < 4; ++i) {
            const unsigned v = w[tid * 4 + i];
            if (v > 1u) atomicAdd(&bad01, 1);
            if (v != 0u && v != 0x3F800000u) atomicAdd(&badf, 1);
        }
        __syncthreads();
        const int fmt = (bad01 == 0) ? 0 : ((badf == 0) ? 1 : 2); // 0=i32,1=f32,2=u8
        for (int i = tid; i < 4096; i += 256) {
            bool on;
            if (fmt == 2) on = (((const unsigned char*)mraw)[i] != 0);
            else          on = (w[i] != 0u);
            mbias[i] = on ? 0.f : -1e30f;
        }
    }
}

// ---------------- bf16 MFMA GEMM, double-buffered prefetch (attn-style) --------
#define QSTAGE(SEL, K0_) do {                                                    \
    _Pragma("unroll") for (int rnd_ = 0; rnd_ < 4; ++rnd_) {                     \
        const int off_ = rnd_ * 4096 + wid * 1024 + lane * 16;                   \
        const int row_ = off_ >> 7;                                              \
        const int ch_  = ((off_ >> 4) & 7) ^ (row_ & 7);                         \
        gload16((const char*)Ag + ((size_t)(n0 + row_) * 1024 + (K0_) + ch_ * 8) * 2, \
                Asm + (SEL) * 16384 + rnd_ * 4096 + wid * 1024);                 \
        gload16((const char*)Bg + ((size_t)(m0 + row_) * 1024 + (K0_) + ch_ * 8) * 2, \
                Bsm + (SEL) * 16384 + rnd_ * 4096 + wid * 1024);                 \
    }                                                                            \
} while (0)

__launch_bounds__(256)
__global__ void qkv_mfma_kernel(const __hip_bfloat16* __restrict__ XB,
                                const __hip_bfloat16* __restrict__ WT,
                                const float* __restrict__ bq, const float* __restrict__ bk,
                                const float* __restrict__ bv,
                                const float* __restrict__ fc, const float* __restrict__ fs,
                                __hip_bfloat16* __restrict__ QB,
                                __hip_bfloat16* __restrict__ KB,
                                __hip_bfloat16* __restrict__ VT) {
    __shared__ __attribute__((aligned(16))) char Asm[32768];  // 2 x WT rows [128][64k]
    __shared__ __attribute__((aligned(16))) char Bsm[32768];  // 2 x XB rows
    const int tid = threadIdx.x;
    const int lane = tid & 63, wid = tid >> 6;
    const int c = lane & 15, g = lane >> 4;
    const int n0 = blockIdx.x * 128, m0 = blockIdx.y * 128;
    const int wn = (wid >> 1) * 64, wm = (wid & 1) * 64;
    const __hip_bfloat16* Ag = WT;
    const __hip_bfloat16* Bg = XB;

    f32x4 acc[4][4];
#pragma unroll
    for (int ni = 0; ni < 4; ++ni)
#pragma unroll
        for (int mj = 0; mj < 4; ++mj) acc[ni][mj] = f32x4{0.f, 0.f, 0.f, 0.f};

    QSTAGE(0, 0);
    int cur = 0;
    for (int kt = 0; kt < 16; ++kt) {
        const int k0 = kt * 64;
        if (kt < 15) {
            QSTAGE(cur ^ 1, k0 + 64);
            asm volatile("s_waitcnt vmcnt(8)" ::: "memory");
        } else {
            asm volatile("s_waitcnt vmcnt(0)" ::: "memory");
        }
        __builtin_amdgcn_sched_barrier(0);
        __builtin_amdgcn_s_barrier();
        __builtin_amdgcn_sched_barrier(0);

        const char* Ac = Asm + cur * 16384;
        const char* Bc = Bsm + cur * 16384;
#pragma unroll
        for (int ks = 0; ks < 2; ++ks) {
            bf16x8 af[4], bfr[4];
#pragma unroll
            for (int t = 0; t < 4; ++t) {
                const int sl = ((g + 4 * ks) ^ (c & 7)) << 4;
                af[t]  = *(const bf16x8*)(Ac + (wn + 16 * t + c) * 128 + sl);
                bfr[t] = *(const bf16x8*)(Bc + (wm + 16 * t + c) * 128 + sl);
            }
#pragma unroll
            for (int ni = 0; ni < 4; ++ni)
#pragma unroll
                for (int mj = 0; mj < 4; ++mj)
                    acc[ni][mj] = __builtin_amdgcn_mfma_f32_16x16x32_bf16(
                        af[ni], bfr[mj], acc[ni][mj], 0, 0, 0);
        }
        __builtin_amdgcn_sched_barrier(0);
        __builtin_amdgcn_s_barrier();   // all waves done with buf[cur]
        __builtin_amdgcn_sched_barrier(0);
        cur ^= 1;
    }

#pragma unroll
    for (int ni = 0; ni < 4; ++ni) {
        const int nb = n0 + wn + 16 * ni + 4 * g;
        const float* bias; int nloc;
        if (nb < 1024)      { bias = bq; nloc = nb; }
        else if (nb < 1536) { bias = bk; nloc = nb - 1024; }
        else                { bias = bv; nloc = nb - 1536; }
        const float4 b4 = *(const float4*)&bias[nloc];
        const int h = nloc >> 6, dk = nb & 63;
#pragma unroll
        for (int mj = 0; mj < 4; ++mj) {
            const int tok = m0 + wm + 16 * mj + c;
            const int bb = tok >> 11, sp = tok & 2047;
            float v0 = acc[ni][mj][0] + b4.x;
            float v1 = acc[ni][mj][1] + b4.y;
            float v2 = acc[ni][mj][2] + b4.z;
            float v3 = acc[ni][mj][3] + b4.w;
            if (nb < 1536) {
                const int p = sp * 32 + (dk >> 1);
                const float c0 = fc[p], s0 = fs[p];
                const float c1 = fc[p + 1], s1 = fs[p + 1];
                float o0 = v0 * c0 - v1 * s0, o1 = v0 * s0 + v1 * c0;
                float o2 = v2 * c1 - v3 * s1, o3 = v2 * s1 + v3 * c1;
                uint2 pk;
                if (nb < 1024) {
                    o0 *= QSCALE; o1 *= QSCALE; o2 *= QSCALE; o3 *= QSCALE;
                    pk.x = pack_bf162(o0, o1); pk.y = pack_bf162(o2, o3);
                    *(uint2*)&QB[(size_t)((bb * 16 + h) * 2048 + sp) * 64 + dk] = pk;
                } else {
                    pk.x = pack_bf162(o0, o1); pk.y = pack_bf162(o2, o3);
                    *(uint2*)&KB[(size_t)((bb * 8 + h) * 2048 + sp) * 64 + dk] = pk;
                }
            } else {
                const size_t vb = (size_t)((bb * 8 + h) * 64 + dk) * 2048 + sp;
                VT[vb]          = __float2bfloat16(v0);
                VT[vb + 2048]   = __float2bfloat16(v1);
                VT[vb + 4096]   = __float2bfloat16(v2);
                VT[vb + 6144]   = __float2bfloat16(v3);
            }
        }
    }
}

// ---------------- out projection MFMA, double-buffered prefetch ----------------
__launch_bounds__(256)
__global__ void out_mfma_kernel(const __hip_bfloat16* __restrict__ AOB,
                                const __hip_bfloat16* __restrict__ WoT,
                                const float* __restrict__ bo,
                                float* __restrict__ out) {
    __shared__ __attribute__((aligned(16))) char Asm[32768];
    __shared__ __attribute__((aligned(16))) char Bsm[32768];
    const int tid = threadIdx.x;
    const int lane = tid & 63, wid = tid >> 6;
    const int c = lane & 15, g = lane >> 4;
    const int n0 = blockIdx.x * 128, m0 = blockIdx.y * 128;
    const int wn = (wid >> 1) * 64, wm = (wid & 1) * 64;
    const __hip_bfloat16* Ag = WoT;
    const __hip_bfloat16* Bg = AOB;

    f32x4 acc[4][4];
#pragma unroll
    for (int ni = 0; ni < 4; ++ni)
#pragma unroll
        for (int mj = 0; mj < 4; ++mj) acc[ni][mj] = f32x4{0.f, 0.f, 0.f, 0.f};

    QSTAGE(0, 0);
    int cur = 0;
    for (int kt = 0; kt < 16; ++kt) {
        const int k0 = kt * 64;
        if (kt < 15) {
            QSTAGE(cur ^ 1, k0 + 64);
            asm volatile("s_waitcnt vmcnt(8)" ::: "memory");
        } else {
            asm volatile("s_waitcnt vmcnt(0)" ::: "memory");
        }
        __builtin_amdgcn_sched_barrier(0);
        __builtin_amdgcn_s_barrier();
        __builtin_amdgcn_sched_barrier(0);

        const char* Ac = Asm + cur * 16384;
        const char* Bc = Bsm + cur * 16384;
#pragma unroll
        for (int ks = 0; ks < 2; ++ks) {
            bf16x8 af[4], bfr[4];
#pragma unroll
            for (int t = 0; t < 4; ++t) {
                const int sl = ((g + 4 * ks) ^ (c & 7)) << 4;
                af[t]  = *(const bf16x8*)(Ac + (wn + 16 * t + c) * 128 + sl);
                bfr[t] = *(const bf16x8*)(Bc + (wm + 16 * t + c) * 128 + sl);
            }
#pragma unroll
            for (int ni = 0; ni < 4; ++ni)
#pragma unroll
                for (int mj = 0; mj < 4; ++mj)
                    acc[ni][mj] = __builtin_amdgcn_mfma_f32_16x16x32_bf16(
                        af[ni], bfr[mj], acc[ni][mj], 0, 0, 0);
        }
        __builtin_amdgcn_sched_barrier(0);
        __builtin_amdgcn_s_barrier();
        __builtin_amdgcn_sched_barrier(0);
        cur ^= 1;
    }
#pragma unroll
    for (int ni = 0; ni < 4; ++ni) {
        const int nb = n0 + wn + 16 * ni + 4 * g;
        const float4 b4 = *(const float4*)&bo[nb];
#pragma unroll
        for (int mj = 0; mj < 4; ++mj) {
            const int tok = m0 + wm + 16 * mj + c;
            const f32x4 a = acc[ni][mj];
            const float4 st = make_float4(a[0] + b4.x, a[1] + b4.y,
                                          a[2] + b4.z, a[3] + b4.w);
            *(float4*)&out[(size_t)tok * 1024 + nb] = st;
        }
    }
}

// ---------------- flash attention: K/V ring-3, ONE barrier/tile ----------------
// 512 blocks (XCD-swizzled), 4 waves, 32 q-rows/wave. Bias in LDS (no in-loop
// VMEM-to-reg loads -> counted vmcnt prefetch never drained). l via ones-MFMA.
// Schedule/iter: vmcnt(4) [tile kt landed] -> barrier -> STAGE(kt+2) [writes
// buf (kt-1)%3, safe: all waves past barrier => done reading it] -> compute.

#define STAGE3(T) do {                                                           \
    const int buf_ = (T) % 3;                                                    \
    const int tk0_ = (T) * 64;                                                   \
    _Pragma("unroll") for (int rnd_ = 0; rnd_ < 2; ++rnd_) {                     \
        const int off_ = rnd_ * 4096 + tid * 16;                                 \
        const int row_ = off_ >> 7;                                              \
        const int ch_  = ((off_ >> 4) & 7) ^ (row_ & 7);                         \
        gload16(Kh + (size_t)(tk0_ + row_) * 64 + ch_ * 8,                       \
                Ksm + buf_ * 8192 + rnd_ * 4096 + wid * 1024);                   \
        gload16(Vh + (size_t)row_ * 2048 + tk0_ + ch_ * 8,                       \
                Vsm + buf_ * 8192 + rnd_ * 4096 + wid * 1024);                   \
    }                                                                            \
} while (0)

__launch_bounds__(256)
__global__ void attn_kernel(const __hip_bfloat16* __restrict__ QB,
                            const __hip_bfloat16* __restrict__ KB,
                            const __hip_bfloat16* __restrict__ VT,
                            const float* __restrict__ maskb,
                            __hip_bfloat16* __restrict__ AOB) {
    __shared__ __attribute__((aligned(16))) char Ksm[24576];   // 3 x [64 key][64 d]
    __shared__ __attribute__((aligned(16))) char Vsm[24576];   // 3 x [64 d][64 key]
    __shared__ char P_lds[4][4096];    // per wave: 2 rt x [16 q][64 key] bf16
    __shared__ float bias_sm[2048];

    const int tid  = threadIdx.x;
    const int lane = tid & 63, wid = tid >> 6;
    const int c = lane & 15, g = lane >> 4;

    // XCD-aware swizzle: 512 blocks, 64 consecutive per XCD (2 KV heads/XCD L2)
    const int bid = blockIdx.x;
    const int o_  = (bid & 7) * 64 + (bid >> 3);
    const int qx = o_ & 15, h = (o_ >> 4) & 15, b = o_ >> 8;
    const int qb = qx * 128 + wid * 32;

    const __hip_bfloat16* Qh = QB + (size_t)(b * 16 + h)       * 2048 * 64;
    const __hip_bfloat16* Kh = KB + (size_t)(b * 8 + (h >> 1)) * 2048 * 64;
    const __hip_bfloat16* Vh = VT + (size_t)(b * 8 + (h >> 1)) * 64 * 2048;
    const float* mb = maskb + b * 2048;

    // prologue: bq regs, bias -> LDS, prefetch tiles 0,1; one full drain here only
    bf16x8 bq[2][2];
#pragma unroll
    for (int rt = 0; rt < 2; ++rt)
#pragma unroll
        for (int ks = 0; ks < 2; ++ks)
            bq[rt][ks] = *(const bf16x8*)&Qh[(size_t)(qb + 16 * rt + c) * 64
                                             + 32 * ks + 8 * g];
    for (int i = tid; i < 512; i += 256)
        *(float4*)&bias_sm[4 * i] = *(const float4*)&mb[4 * i];
    STAGE3(0);
    STAGE3(1);
    __syncthreads();   // drains prologue loads once; bias_sm + tiles 0,1 visible

    const short oneb = (short)0x3F80;
    const bf16x8 ones = {oneb, oneb, oneb, oneb, oneb, oneb, oneb, oneb};

    f32x4 o[2][4];
    f32x4 lacc[2];
#pragma unroll
    for (int rt = 0; rt < 2; ++rt) {
        lacc[rt] = f32x4{0.f, 0.f, 0.f, 0.f};
#pragma unroll
        for (int mt = 0; mt < 4; ++mt) o[rt][mt] = f32x4{0.f, 0.f, 0.f, 0.f};
    }
    float m_[2] = {-INFINITY, -INFINITY};

    char* Pw = &P_lds[wid][0];
    const int swz = (c & 7) << 4;

    for (int kt = 0; kt < 32; ++kt) {
        const int k0 = kt * 64;
        if (kt < 31) {
            asm volatile("s_waitcnt vmcnt(4)" ::: "memory");
        } else {
            asm volatile("s_waitcnt vmcnt(0)" ::: "memory");
        }
        __builtin_amdgcn_sched_barrier(0);
        __builtin_amdgcn_s_barrier();
        __builtin_amdgcn_sched_barrier(0);
        if (kt < 30) STAGE3(kt + 2);      // writes buf (kt-1)%3: safe after barrier

        const char* Kc = Ksm + (kt % 3) * 8192;
        const char* Vc = Vsm + (kt % 3) * 8192;

        // K frags from LDS
        bf16x8 ak[4][2];
#pragma unroll
        for (int mt = 0; mt < 4; ++mt)
#pragma unroll
            for (int ks = 0; ks < 2; ++ks)
                ak[mt][ks] = *(const bf16x8*)(Kc + (16 * mt + c) * 128
                                              + (((g + 4 * ks) ^ (c & 7)) << 4));

        // mask bias from LDS (broadcast within g-group; no VMEM in-loop)
        const bool needb = (k0 + 63 > qb);
        float4 biasv[4];
        if (needb) {
#pragma unroll
            for (int mt = 0; mt < 4; ++mt)
                biasv[mt] = *(const float4*)&bias_sm[k0 + 16 * mt + 4 * g];
        }

        __builtin_amdgcn_s_setprio(1);
        f32x4 st[2][4];
#pragma unroll
        for (int rt = 0; rt < 2; ++rt)
#pragma unroll
            for (int mt = 0; mt < 4; ++mt) {
                f32x4 z = f32x4{0.f, 0.f, 0.f, 0.f};
                z = __builtin_amdgcn_mfma_f32_16x16x32_bf16(ak[mt][0], bq[rt][0], z, 0, 0, 0);
                z = __builtin_amdgcn_mfma_f32_16x16x32_bf16(ak[mt][1], bq[rt][1], z, 0, 0, 0);
                st[rt][mt] = z;
            }
        __builtin_amdgcn_s_setprio(0);

        // V frags from LDS (in flight during softmax)
        bf16x8 av[4][2];
#pragma unroll
        for (int mt = 0; mt < 4; ++mt)
#pragma unroll
            for (int ks = 0; ks < 2; ++ks)
                av[mt][ks] = *(const bf16x8*)(Vc + (16 * mt + c) * 128
                                              + (((g + 4 * ks) ^ (c & 7)) << 4));

        // ---- softmax + P-write for both rt ----
#pragma unroll
        for (int rt = 0; rt < 2; ++rt) {
            const int qw = qb + 16 * rt;
            if (k0 + 63 <= qw) {
                // fully causal: no mask work
            } else if (k0 > qw + 15) {             // fully future: +bias only
#pragma unroll
                for (int mt = 0; mt < 4; ++mt) {
                    st[rt][mt][0] += biasv[mt].x; st[rt][mt][1] += biasv[mt].y;
                    st[rt][mt][2] += biasv[mt].z; st[rt][mt][3] += biasv[mt].w;
                }
            } else {                               // mixed (diagonal) tile
                const int qg = qw + c;
#pragma unroll
                for (int mt = 0; mt < 4; ++mt) {
                    const float bvr[4] = {biasv[mt].x, biasv[mt].y,
                                          biasv[mt].z, biasv[mt].w};
#pragma unroll
                    for (int r = 0; r < 4; ++r) {
                        const int kg = k0 + 16 * mt + 4 * g + r;
                        st[rt][mt][r] += (kg <= qg) ? 0.f : bvr[r];
                    }
                }
            }
            // tree max (depth ~4 instead of 15-deep chain)
            float mx[4];
#pragma unroll
            for (int mt = 0; mt < 4; ++mt)
                mx[mt] = fmaxf(fmaxf(st[rt][mt][0], st[rt][mt][1]),
                               fmaxf(st[rt][mt][2], st[rt][mt][3]));
            float pmax = fmaxf(fmaxf(mx[0], mx[1]), fmaxf(mx[2], mx[3]));
            pmax = fmaxf(pmax, __shfl_xor(pmax, 16));
            pmax = fmaxf(pmax, __shfl_xor(pmax, 32));
            if (!__all(pmax <= m_[rt] + 11.5f)) {  // defer-rescale (T13)
                const float mn = fmaxf(m_[rt], pmax);
                const float alpha = exp2_fast(m_[rt] - mn);
                m_[rt] = mn;
                lacc[rt][0] *= alpha;              // only reg0 of lacc is read
#pragma unroll
                for (int mt = 0; mt < 4; ++mt) o[rt][mt] *= alpha;
            }
#pragma unroll
            for (int mt = 0; mt < 4; ++mt)
#pragma unroll
                for (int r = 0; r < 4; ++r)
                    st[rt][mt][r] = exp2_fast(st[rt][mt][r] - m_[rt]);

            char* Pr = Pw + rt * 2048 + c * 128;
#pragma unroll
            for (int mt = 0; mt < 4; ++mt) {
                const unsigned w0 = pack_bf162(st[rt][mt][0], st[rt][mt][1]);
                const unsigned w1 = pack_bf162(st[rt][mt][2], st[rt][mt][3]);
                *(unsigned long long*)(Pr + ((32 * mt + 8 * g) ^ swz)) =
                    (unsigned long long)w0 | ((unsigned long long)w1 << 32);
            }
        }

        // ---- P-read + PV + l-MFMA for both rt ----
#pragma unroll
        for (int rt = 0; rt < 2; ++rt) {
            const char* Pr = Pw + rt * 2048 + c * 128;
            const bf16x8 pb0 = *(const bf16x8*)(Pr + ((16 * g) ^ swz));
            const bf16x8 pb1 = *(const bf16x8*)(Pr + ((64 + 16 * g) ^ swz));
            __builtin_amdgcn_s_setprio(1);
#pragma unroll
            for (int mt = 0; mt < 4; ++mt) {
                o[rt][mt] = __builtin_amdgcn_mfma_f32_16x16x32_bf16(av[mt][0], pb0, o[rt][mt], 0, 0, 0);
                o[rt][mt] = __builtin_amdgcn_mfma_f32_16x16x32_bf16(av[mt][1], pb1, o[rt][mt], 0, 0, 0);
            }
            lacc[rt] = __builtin_amdgcn_mfma_f32_16x16x32_bf16(ones, pb0, lacc[rt], 0, 0, 0);
            lacc[rt] = __builtin_amdgcn_mfma_f32_16x16x32_bf16(ones, pb1, lacc[rt], 0, 0, 0);
            __builtin_amdgcn_s_setprio(0);
        }
        // single barrier per tile (top of next iteration)
    }

#pragma unroll
    for (int rt = 0; rt < 2; ++rt) {
        const float inv = 1.f / lacc[rt][0];
        const size_t tok = (size_t)(b * 2048 + qb + 16 * rt + c);
#pragma unroll
        for (int mt = 0; mt < 4; ++mt) {
            uint2 pk;
            pk.x = pack_bf162(o[rt][mt][0] * inv, o[rt][mt][1] * inv);
            pk.y = pack_bf162(o[rt][mt][2] * inv, o[rt][mt][3] * inv);
            *(uint2*)&AOB[tok * 1024 + h * 64 + 16 * mt + 4 * g] = pk;
        }
    }
}

extern "C" void kernel_launch(void* const* d_in, const int* in_sizes, int n_in,
                              void* d_out, int out_size, void* d_ws, size_t ws_size,
                              hipStream_t stream) {
    const float* x  = (const float*)d_in[0];
    const float* Wq = (const float*)d_in[1];
    const float* bq = (const float*)d_in[2];
    const float* Wk = (const float*)d_in[3];
    const float* bk = (const float*)d_in[4];
    const float* Wv = (const float*)d_in[5];
    const float* bv = (const float*)d_in[6];
    const float* Wo = (const float*)d_in[7];
    const float* bo = (const float*)d_in[8];
    const float* fc = (const float*)d_in[9];
    const float* fs = (const float*)d_in[10];
    const void*  am = d_in[11];

    char* ws = (char*)d_ws;
    __hip_bfloat16* XB  = (__hip_bfloat16*)(ws + OFF_XB);
    __hip_bfloat16* WT  = (__hip_bfloat16*)(ws + OFF_WT);
    __hip_bfloat16* WoT = (__hip_bfloat16*)(ws + OFF_WO);
    __hip_bfloat16* QB  = (__hip_bfloat16*)(ws + OFF_QB);
    __hip_bfloat16* KB  = (__hip_bfloat16*)(ws + OFF_KB);
    __hip_bfloat16* VT  = (__hip_bfloat16*)(ws + OFF_VT);
    __hip_bfloat16* AOB = (__hip_bfloat16*)(ws + OFF_AO);
    float* mbias = (float*)(ws + OFF_MB);
    float* out   = (float*)d_out;

    hipLaunchKernelGGL(prep_kernel, dim3(4097), dim3(256), 0, stream,
                       x, Wq, Wk, Wv, Wo, am, XB, WT, WoT, mbias);
    hipLaunchKernelGGL(qkv_mfma_kernel, dim3(16, 32), dim3(256), 0, stream,
                       XB, WT, bq, bk, bv, fc, fs, QB, KB, VT);
    hipLaunchKernelGGL(attn_kernel, dim3(512), dim3(256), 0, stream,
                       QB, KB, VT, mbias, AOB);
    hipLaunchKernelGGL(out_mfma_kernel, dim3(8, 32), dim3(256), 0, stream,
                       AOB, WoT, bo, out);
}

// Round 13
// 141.343 us; speedup vs baseline: 1.0293x; 1.0293x over previous
//
#include <hip/hip_runtime.h>
#include <hip/hip_bf16.h>
#include <math.h>

// Problem constants: B=2, S=2048, D=1024, HQ=16, HKV=8, DK=DV=64
typedef __attribute__((ext_vector_type(8))) short bf16x8;   // 8 bf16 (4 VGPRs)
typedef __attribute__((ext_vector_type(4))) float f32x4;

// ws layout (byte offsets)
#define OFF_XB  0ull             // bf16 [4096][1024]   8 MB
#define OFF_WT  (8ull<<20)       // bf16 [2048][1024]   4 MB  ([Wq|Wk|Wv]^T)
#define OFF_WO  (12ull<<20)      // bf16 [1024][1024]   2 MB  (Wo^T)
#define OFF_QB  (14ull<<20)      // bf16 [2][16][2048][64]  8 MB (RoPE'd, scaled 1/8*log2e)
#define OFF_KB  (22ull<<20)      // bf16 [2][8][2048][64]   4 MB (RoPE'd)
#define OFF_VT  (26ull<<20)      // bf16 [2][8][64][2048]   4 MB (V^T)
#define OFF_AO  (30ull<<20)      // bf16 [4096][1024]   8 MB (attn out)
#define OFF_MB  (38ull<<20)      // f32  [2][2048] mask bias (0 / -1e30)

#define QSCALE 0.18033688056680276f   // 0.125 * log2(e): softmax in exp2 domain

__device__ inline unsigned pack_bf162(float a, float b) {
    __hip_bfloat162 t = __float22bfloat162_rn(make_float2(a, b));  // a -> low 16 bits
    return *(unsigned*)&t;
}

__device__ inline float exp2_fast(float x) {
    float r;
    asm("v_exp_f32 %0, %1" : "=v"(r) : "v"(x));
    return r;
}

__device__ inline void gload16(const void* g, void* l) {
    __builtin_amdgcn_global_load_lds(
        (const __attribute__((address_space(1))) void*)g,
        (__attribute__((address_space(3))) void*)l, 16, 0, 0);
}

// ---------------- prep: x->bf16, W transposes->bf16, mask canon ----------------
__launch_bounds__(256)
__global__ void prep_kernel(const float* __restrict__ x,
                            const float* __restrict__ Wq, const float* __restrict__ Wk,
                            const float* __restrict__ Wv, const float* __restrict__ Wo,
                            const void* __restrict__ mraw,
                            __hip_bfloat16* __restrict__ XB,
                            __hip_bfloat16* __restrict__ WT,
                            __hip_bfloat16* __restrict__ WoT,
                            float* __restrict__ mbias) {
    __shared__ float T[32][33];
    __shared__ int bad01, badf;
    const int tid = threadIdx.x;
    const int bid = blockIdx.x;
    if (bid < 1024) {                       // x -> bf16
        const int base = bid * 4096;
#pragma unroll
        for (int i = 0; i < 4; ++i) {
            const int e = base + (i * 256 + tid) * 4;
            const float4 v = *(const float4*)&x[e];
            uint2 pk;
            pk.x = pack_bf162(v.x, v.y);
            pk.y = pack_bf162(v.z, v.w);
            *(uint2*)&XB[e] = pk;
        }
    } else if (bid < 4096) {                // W transposes
        const float* src; int ldn, nbase; __hip_bfloat16* dst; int n0, k0;
        if (bid < 3072) {
            const int tb = bid - 1024;
            const int kt = tb >> 6, nt = tb & 63;
            n0 = nt * 32; k0 = kt * 32; dst = WT;
            if (n0 < 1024)      { src = Wq; ldn = 1024; nbase = n0; }
            else if (n0 < 1536) { src = Wk; ldn = 512;  nbase = n0 - 1024; }
            else                { src = Wv; ldn = 512;  nbase = n0 - 1536; }
        } else {
            const int tb = bid - 3072;
            const int kt = tb >> 5, nt = tb & 31;
            n0 = nt * 32; k0 = kt * 32; dst = WoT;
            src = Wo; ldn = 1024; nbase = n0;
        }
        const int c = tid & 31, r0 = tid >> 5;
#pragma unroll
        for (int i = 0; i < 4; ++i)
            T[r0 + 8 * i][c] = src[(size_t)(k0 + r0 + 8 * i) * ldn + nbase + c];
        __syncthreads();
#pragma unroll
        for (int i = 0; i < 4; ++i) {
            const int nn = r0 + 8 * i;
            dst[(size_t)(n0 + nn) * 1024 + k0 + c] = __float2bfloat16(T[c][nn]);
        }
    } else {                                // mask canonicalization
        if (tid == 0) { bad01 = 0; badf = 0; }
        __syncthreads();
        const unsigned* w = (const unsigned*)mraw;
#pragma unroll
        for (int i = 0; i < 4; ++i) {
            const unsigned v = w[tid * 4 + i];
            if (v > 1u) atomicAdd(&bad01, 1);
            if (v != 0u && v != 0x3F800000u) atomicAdd(&badf, 1);
        }
        __syncthreads();
        const int fmt = (bad01 == 0) ? 0 : ((badf == 0) ? 1 : 2); // 0=i32,1=f32,2=u8
        for (int i = tid; i < 4096; i += 256) {
            bool on;
            if (fmt == 2) on = (((const unsigned char*)mraw)[i] != 0);
            else          on = (w[i] != 0u);
            mbias[i] = on ? 0.f : -1e30f;
        }
    }
}

// ---------------- bf16 MFMA GEMM, double-buffered prefetch (attn-style) --------
#define QSTAGE(SEL, K0_) do {                                                    \
    _Pragma("unroll") for (int rnd_ = 0; rnd_ < 4; ++rnd_) {                     \
        const int off_ = rnd_ * 4096 + wid * 1024 + lane * 16;                   \
        const int row_ = off_ >> 7;                                              \
        const int ch_  = ((off_ >> 4) & 7) ^ (row_ & 7);                         \
        gload16((const char*)Ag + ((size_t)(n0 + row_) * 1024 + (K0_) + ch_ * 8) * 2, \
                Asm + (SEL) * 16384 + rnd_ * 4096 + wid * 1024);                 \
        gload16((const char*)Bg + ((size_t)(m0 + row_) * 1024 + (K0_) + ch_ * 8) * 2, \
                Bsm + (SEL) * 16384 + rnd_ * 4096 + wid * 1024);                 \
    }                                                                            \
} while (0)

__launch_bounds__(256)
__global__ void qkv_mfma_kernel(const __hip_bfloat16* __restrict__ XB,
                                const __hip_bfloat16* __restrict__ WT,
                                const float* __restrict__ bq, const float* __restrict__ bk,
                                const float* __restrict__ bv,
                                const float* __restrict__ fc, const float* __restrict__ fs,
                                __hip_bfloat16* __restrict__ QB,
                                __hip_bfloat16* __restrict__ KB,
                                __hip_bfloat16* __restrict__ VT) {
    __shared__ __attribute__((aligned(16))) char Asm[32768];  // 2 x WT rows [128][64k]
    __shared__ __attribute__((aligned(16))) char Bsm[32768];  // 2 x XB rows
    const int tid = threadIdx.x;
    const int lane = tid & 63, wid = tid >> 6;
    const int c = lane & 15, g = lane >> 4;
    const int n0 = blockIdx.x * 128, m0 = blockIdx.y * 128;
    const int wn = (wid >> 1) * 64, wm = (wid & 1) * 64;
    const __hip_bfloat16* Ag = WT;
    const __hip_bfloat16* Bg = XB;

    f32x4 acc[4][4];
#pragma unroll
    for (int ni = 0; ni < 4; ++ni)
#pragma unroll
        for (int mj = 0; mj < 4; ++mj) acc[ni][mj] = f32x4{0.f, 0.f, 0.f, 0.f};

    QSTAGE(0, 0);
    int cur = 0;
    for (int kt = 0; kt < 16; ++kt) {
        const int k0 = kt * 64;
        if (kt < 15) {
            QSTAGE(cur ^ 1, k0 + 64);
            asm volatile("s_waitcnt vmcnt(8)" ::: "memory");
        } else {
            asm volatile("s_waitcnt vmcnt(0)" ::: "memory");
        }
        __builtin_amdgcn_sched_barrier(0);
        __builtin_amdgcn_s_barrier();
        __builtin_amdgcn_sched_barrier(0);

        const char* Ac = Asm + cur * 16384;
        const char* Bc = Bsm + cur * 16384;
#pragma unroll
        for (int ks = 0; ks < 2; ++ks) {
            bf16x8 af[4], bfr[4];
#pragma unroll
            for (int t = 0; t < 4; ++t) {
                const int sl = ((g + 4 * ks) ^ (c & 7)) << 4;
                af[t]  = *(const bf16x8*)(Ac + (wn + 16 * t + c) * 128 + sl);
                bfr[t] = *(const bf16x8*)(Bc + (wm + 16 * t + c) * 128 + sl);
            }
#pragma unroll
            for (int ni = 0; ni < 4; ++ni)
#pragma unroll
                for (int mj = 0; mj < 4; ++mj)
                    acc[ni][mj] = __builtin_amdgcn_mfma_f32_16x16x32_bf16(
                        af[ni], bfr[mj], acc[ni][mj], 0, 0, 0);
        }
        __builtin_amdgcn_sched_barrier(0);
        __builtin_amdgcn_s_barrier();   // all waves done with buf[cur]
        __builtin_amdgcn_sched_barrier(0);
        cur ^= 1;
    }

#pragma unroll
    for (int ni = 0; ni < 4; ++ni) {
        const int nb = n0 + wn + 16 * ni + 4 * g;
        const float* bias; int nloc;
        if (nb < 1024)      { bias = bq; nloc = nb; }
        else if (nb < 1536) { bias = bk; nloc = nb - 1024; }
        else                { bias = bv; nloc = nb - 1536; }
        const float4 b4 = *(const float4*)&bias[nloc];
        const int h = nloc >> 6, dk = nb & 63;
#pragma unroll
        for (int mj = 0; mj < 4; ++mj) {
            const int tok = m0 + wm + 16 * mj + c;
            const int bb = tok >> 11, sp = tok & 2047;
            float v0 = acc[ni][mj][0] + b4.x;
            float v1 = acc[ni][mj][1] + b4.y;
            float v2 = acc[ni][mj][2] + b4.z;
            float v3 = acc[ni][mj][3] + b4.w;
            if (nb < 1536) {
                const int p = sp * 32 + (dk >> 1);
                const float c0 = fc[p], s0 = fs[p];
                const float c1 = fc[p + 1], s1 = fs[p + 1];
                float o0 = v0 * c0 - v1 * s0, o1 = v0 * s0 + v1 * c0;
                float o2 = v2 * c1 - v3 * s1, o3 = v2 * s1 + v3 * c1;
                uint2 pk;
                if (nb < 1024) {
                    o0 *= QSCALE; o1 *= QSCALE; o2 *= QSCALE; o3 *= QSCALE;
                    pk.x = pack_bf162(o0, o1); pk.y = pack_bf162(o2, o3);
                    *(uint2*)&QB[(size_t)((bb * 16 + h) * 2048 + sp) * 64 + dk] = pk;
                } else {
                    pk.x = pack_bf162(o0, o1); pk.y = pack_bf162(o2, o3);
                    *(uint2*)&KB[(size_t)((bb * 8 + h) * 2048 + sp) * 64 + dk] = pk;
                }
            } else {
                const size_t vb = (size_t)((bb * 8 + h) * 64 + dk) * 2048 + sp;
                VT[vb]          = __float2bfloat16(v0);
                VT[vb + 2048]   = __float2bfloat16(v1);
                VT[vb + 4096]   = __float2bfloat16(v2);
                VT[vb + 6144]   = __float2bfloat16(v3);
            }
        }
    }
}

// ---------------- out projection MFMA, double-buffered prefetch ----------------
__launch_bounds__(256)
__global__ void out_mfma_kernel(const __hip_bfloat16* __restrict__ AOB,
                                const __hip_bfloat16* __restrict__ WoT,
                                const float* __restrict__ bo,
                                float* __restrict__ out) {
    __shared__ __attribute__((aligned(16))) char Asm[32768];
    __shared__ __attribute__((aligned(16))) char Bsm[32768];
    const int tid = threadIdx.x;
    const int lane = tid & 63, wid = tid >> 6;
    const int c = lane & 15, g = lane >> 4;
    const int n0 = blockIdx.x * 128, m0 = blockIdx.y * 128;
    const int wn = (wid >> 1) * 64, wm = (wid & 1) * 64;
    const __hip_bfloat16* Ag = WoT;
    const __hip_bfloat16* Bg = AOB;

    f32x4 acc[4][4];
#pragma unroll
    for (int ni = 0; ni < 4; ++ni)
#pragma unroll
        for (int mj = 0; mj < 4; ++mj) acc[ni][mj] = f32x4{0.f, 0.f, 0.f, 0.f};

    QSTAGE(0, 0);
    int cur = 0;
    for (int kt = 0; kt < 16; ++kt) {
        const int k0 = kt * 64;
        if (kt < 15) {
            QSTAGE(cur ^ 1, k0 + 64);
            asm volatile("s_waitcnt vmcnt(8)" ::: "memory");
        } else {
            asm volatile("s_waitcnt vmcnt(0)" ::: "memory");
        }
        __builtin_amdgcn_sched_barrier(0);
        __builtin_amdgcn_s_barrier();
        __builtin_amdgcn_sched_barrier(0);

        const char* Ac = Asm + cur * 16384;
        const char* Bc = Bsm + cur * 16384;
#pragma unroll
        for (int ks = 0; ks < 2; ++ks) {
            bf16x8 af[4], bfr[4];
#pragma unroll
            for (int t = 0; t < 4; ++t) {
                const int sl = ((g + 4 * ks) ^ (c & 7)) << 4;
                af[t]  = *(const bf16x8*)(Ac + (wn + 16 * t + c) * 128 + sl);
                bfr[t] = *(const bf16x8*)(Bc + (wm + 16 * t + c) * 128 + sl);
            }
#pragma unroll
            for (int ni = 0; ni < 4; ++ni)
#pragma unroll
                for (int mj = 0; mj < 4; ++mj)
                    acc[ni][mj] = __builtin_amdgcn_mfma_f32_16x16x32_bf16(
                        af[ni], bfr[mj], acc[ni][mj], 0, 0, 0);
        }
        __builtin_amdgcn_sched_barrier(0);
        __builtin_amdgcn_s_barrier();
        __builtin_amdgcn_sched_barrier(0);
        cur ^= 1;
    }
#pragma unroll
    for (int ni = 0; ni < 4; ++ni) {
        const int nb = n0 + wn + 16 * ni + 4 * g;
        const float4 b4 = *(const float4*)&bo[nb];
#pragma unroll
        for (int mj = 0; mj < 4; ++mj) {
            const int tok = m0 + wm + 16 * mj + c;
            const f32x4 a = acc[ni][mj];
            const float4 st = make_float4(a[0] + b4.x, a[1] + b4.y,
                                          a[2] + b4.z, a[3] + b4.w);
            *(float4*)&out[(size_t)tok * 1024 + nb] = st;
        }
    }
}

// ---------------- flash attention (R11 structure + packed-f32 softmax) ---------
// 512 blocks (XCD-swizzled), 4 waves, 32 q-rows/wave, LDS K/V dbuf, dual-P,
// l via ones-MFMA. Softmax arithmetic in f32x4 vector form so LLVM can emit
// v_pk_add_f32 / v_pk_max_f32 (halves issue slots on the every-tile path).

#define STAGE(BUFSEL, K0_) do {                                                  \
    _Pragma("unroll") for (int rnd_ = 0; rnd_ < 2; ++rnd_) {                     \
        const int off_ = rnd_ * 4096 + tid * 16;                                 \
        const int row_ = off_ >> 7;                                              \
        const int ch_  = ((off_ >> 4) & 7) ^ (row_ & 7);                         \
        gload16(Kh + (size_t)((K0_) + row_) * 64 + ch_ * 8,                      \
                Ksm + (BUFSEL) * 8192 + rnd_ * 4096 + wid * 1024);               \
        gload16(Vh + (size_t)row_ * 2048 + (K0_) + ch_ * 8,                      \
                Vsm + (BUFSEL) * 8192 + rnd_ * 4096 + wid * 1024);               \
    }                                                                            \
} while (0)

__launch_bounds__(256)
__global__ void attn_kernel(const __hip_bfloat16* __restrict__ QB,
                            const __hip_bfloat16* __restrict__ KB,
                            const __hip_bfloat16* __restrict__ VT,
                            const float* __restrict__ maskb,
                            __hip_bfloat16* __restrict__ AOB) {
    __shared__ __attribute__((aligned(16))) char Ksm[16384];   // 2 x [64 key][64 d]
    __shared__ __attribute__((aligned(16))) char Vsm[16384];   // 2 x [64 d][64 key]
    __shared__ char P_lds[4][4096];    // per wave: 2 rt x [16 q][64 key] bf16

    const int tid  = threadIdx.x;
    const int lane = tid & 63, wid = tid >> 6;
    const int c = lane & 15, g = lane >> 4;

    // XCD-aware swizzle: 512 blocks, 64 consecutive per XCD (2 KV heads/XCD L2)
    const int bid = blockIdx.x;
    const int o_  = (bid & 7) * 64 + (bid >> 3);
    const int qx = o_ & 15, h = (o_ >> 4) & 15, b = o_ >> 8;
    const int qb = qx * 128 + wid * 32;

    const __hip_bfloat16* Qh = QB + (size_t)(b * 16 + h)       * 2048 * 64;
    const __hip_bfloat16* Kh = KB + (size_t)(b * 8 + (h >> 1)) * 2048 * 64;
    const __hip_bfloat16* Vh = VT + (size_t)(b * 8 + (h >> 1)) * 64 * 2048;
    const float* mb = maskb + b * 2048;

    STAGE(0, 0);

    bf16x8 bq[2][2];
#pragma unroll
    for (int rt = 0; rt < 2; ++rt)
#pragma unroll
        for (int ks = 0; ks < 2; ++ks)
            bq[rt][ks] = *(const bf16x8*)&Qh[(size_t)(qb + 16 * rt + c) * 64
                                             + 32 * ks + 8 * g];
    __syncthreads();   // stage0 + bq complete

    const short oneb = (short)0x3F80;
    const bf16x8 ones = {oneb, oneb, oneb, oneb, oneb, oneb, oneb, oneb};

    f32x4 o[2][4];
    f32x4 lacc[2];
#pragma unroll
    for (int rt = 0; rt < 2; ++rt) {
        lacc[rt] = f32x4{0.f, 0.f, 0.f, 0.f};
#pragma unroll
        for (int mt = 0; mt < 4; ++mt) o[rt][mt] = f32x4{0.f, 0.f, 0.f, 0.f};
    }
    float m_[2] = {-INFINITY, -INFINITY};

    char* Pw = &P_lds[wid][0];
    const int swz = (c & 7) << 4;

    int cur = 0;
    for (int kt = 0; kt < 32; ++kt) {
        const int k0 = kt * 64;
        if (kt < 31) {
            STAGE(cur ^ 1, k0 + 64);
            asm volatile("s_waitcnt vmcnt(4)" ::: "memory");
        } else {
            asm volatile("s_waitcnt vmcnt(0)" ::: "memory");
        }
        __builtin_amdgcn_sched_barrier(0);
        __builtin_amdgcn_s_barrier();
        __builtin_amdgcn_sched_barrier(0);

        const char* Kc = Ksm + cur * 8192;
        const char* Vc = Vsm + cur * 8192;

        // K frags from LDS
        bf16x8 ak[4][2];
#pragma unroll
        for (int mt = 0; mt < 4; ++mt)
#pragma unroll
            for (int ks = 0; ks < 2; ++ks)
                ak[mt][ks] = *(const bf16x8*)(Kc + (16 * mt + c) * 128
                                              + (((g + 4 * ks) ^ (c & 7)) << 4));

        // mask-bias loads issued early (L2-hot; latency hides under QK MFMAs)
        const bool needb = (k0 + 63 > qb);
        f32x4 bv4[4];
        if (needb) {
#pragma unroll
            for (int mt = 0; mt < 4; ++mt)
                bv4[mt] = *(const f32x4*)&mb[k0 + 16 * mt + 4 * g];
        }

        __builtin_amdgcn_s_setprio(1);
        f32x4 st[2][4];
#pragma unroll
        for (int rt = 0; rt < 2; ++rt)
#pragma unroll
            for (int mt = 0; mt < 4; ++mt) {
                f32x4 z = f32x4{0.f, 0.f, 0.f, 0.f};
                z = __builtin_amdgcn_mfma_f32_16x16x32_bf16(ak[mt][0], bq[rt][0], z, 0, 0, 0);
                z = __builtin_amdgcn_mfma_f32_16x16x32_bf16(ak[mt][1], bq[rt][1], z, 0, 0, 0);
                st[rt][mt] = z;
            }
        __builtin_amdgcn_s_setprio(0);

        // V frags from LDS (in flight during softmax)
        bf16x8 av[4][2];
#pragma unroll
        for (int mt = 0; mt < 4; ++mt)
#pragma unroll
            for (int ks = 0; ks < 2; ++ks)
                av[mt][ks] = *(const bf16x8*)(Vc + (16 * mt + c) * 128
                                              + (((g + 4 * ks) ^ (c & 7)) << 4));

        // ---- softmax + P-write for both rt (vectorized arithmetic) ----
#pragma unroll
        for (int rt = 0; rt < 2; ++rt) {
            const int qw = qb + 16 * rt;
            if (k0 + 63 <= qw) {
                // fully causal: no mask work
            } else if (k0 > qw + 15) {             // fully future: vector bias add
#pragma unroll
                for (int mt = 0; mt < 4; ++mt)
                    st[rt][mt] = st[rt][mt] + bv4[mt];
            } else {                               // mixed (diagonal) tile
                const int qg = qw + c;
#pragma unroll
                for (int mt = 0; mt < 4; ++mt)
#pragma unroll
                    for (int r = 0; r < 4; ++r) {
                        const int kg = k0 + 16 * mt + 4 * g + r;
                        st[rt][mt][r] += (kg <= qg) ? 0.f : bv4[mt][r];
                    }
            }
            // vector tree max (v_pk_max_f32 capable)
            const f32x4 m01 = __builtin_elementwise_max(st[rt][0], st[rt][1]);
            const f32x4 m23 = __builtin_elementwise_max(st[rt][2], st[rt][3]);
            const f32x4 mv  = __builtin_elementwise_max(m01, m23);
            float pmax = fmaxf(fmaxf(mv[0], mv[1]), fmaxf(mv[2], mv[3]));
            pmax = fmaxf(pmax, __shfl_xor(pmax, 16));
            pmax = fmaxf(pmax, __shfl_xor(pmax, 32));
            if (!__all(pmax <= m_[rt] + 11.5f)) {  // defer-rescale (T13)
                const float mn = fmaxf(m_[rt], pmax);
                const float alpha = exp2_fast(m_[rt] - mn);
                m_[rt] = mn;
                lacc[rt][0] *= alpha;              // only reg0 of lacc is read
#pragma unroll
                for (int mt = 0; mt < 4; ++mt) o[rt][mt] *= alpha;
            }
            const float mneg = m_[rt];
            const f32x4 m4 = {mneg, mneg, mneg, mneg};
#pragma unroll
            for (int mt = 0; mt < 4; ++mt) {
                const f32x4 e = st[rt][mt] - m4;   // vector sub (pk-capable)
#pragma unroll
                for (int r = 0; r < 4; ++r)
                    st[rt][mt][r] = exp2_fast(e[r]);
            }

            char* Pr = Pw + rt * 2048 + c * 128;
#pragma unroll
            for (int mt = 0; mt < 4; ++mt) {
                const unsigned w0 = pack_bf162(st[rt][mt][0], st[rt][mt][1]);
                const unsigned w1 = pack_bf162(st[rt][mt][2], st[rt][mt][3]);
                *(unsigned long long*)(Pr + ((32 * mt + 8 * g) ^ swz)) =
                    (unsigned long long)w0 | ((unsigned long long)w1 << 32);
            }
        }

        // ---- P-read + PV + l-MFMA for both rt ----
#pragma unroll
        for (int rt = 0; rt < 2; ++rt) {
            const char* Pr = Pw + rt * 2048 + c * 128;
            const bf16x8 pb0 = *(const bf16x8*)(Pr + ((16 * g) ^ swz));
            const bf16x8 pb1 = *(const bf16x8*)(Pr + ((64 + 16 * g) ^ swz));
            __builtin_amdgcn_s_setprio(1);
#pragma unroll
            for (int mt = 0; mt < 4; ++mt) {
                o[rt][mt] = __builtin_amdgcn_mfma_f32_16x16x32_bf16(av[mt][0], pb0, o[rt][mt], 0, 0, 0);
                o[rt][mt] = __builtin_amdgcn_mfma_f32_16x16x32_bf16(av[mt][1], pb1, o[rt][mt], 0, 0, 0);
            }
            lacc[rt] = __builtin_amdgcn_mfma_f32_16x16x32_bf16(ones, pb0, lacc[rt], 0, 0, 0);
            lacc[rt] = __builtin_amdgcn_mfma_f32_16x16x32_bf16(ones, pb1, lacc[rt], 0, 0, 0);
            __builtin_amdgcn_s_setprio(0);
        }

        __builtin_amdgcn_sched_barrier(0);
        __builtin_amdgcn_s_barrier();   // all waves done reading buf[cur]
        __builtin_amdgcn_sched_barrier(0);
        cur ^= 1;
    }

#pragma unroll
    for (int rt = 0; rt < 2; ++rt) {
        const float inv = 1.f / lacc[rt][0];
        const size_t tok = (size_t)(b * 2048 + qb + 16 * rt + c);
#pragma unroll
        for (int mt = 0; mt < 4; ++mt) {
            uint2 pk;
            pk.x = pack_bf162(o[rt][mt][0] * inv, o[rt][mt][1] * inv);
            pk.y = pack_bf162(o[rt][mt][2] * inv, o[rt][mt][3] * inv);
            *(uint2*)&AOB[tok * 1024 + h * 64 + 16 * mt + 4 * g] = pk;
        }
    }
}

extern "C" void kernel_launch(void* const* d_in, const int* in_sizes, int n_in,
                              void* d_out, int out_size, void* d_ws, size_t ws_size,
                              hipStream_t stream) {
    const float* x  = (const float*)d_in[0];
    const float* Wq = (const float*)d_in[1];
    const float* bq = (const float*)d_in[2];
    const float* Wk = (const float*)d_in[3];
    const float* bk = (const float*)d_in[4];
    const float* Wv = (const float*)d_in[5];
    const float* bv = (const float*)d_in[6];
    const float* Wo = (const float*)d_in[7];
    const float* bo = (const float*)d_in[8];
    const float* fc = (const float*)d_in[9];
    const float* fs = (const float*)d_in[10];
    const void*  am = d_in[11];

    char* ws = (char*)d_ws;
    __hip_bfloat16* XB  = (__hip_bfloat16*)(ws + OFF_XB);
    __hip_bfloat16* WT  = (__hip_bfloat16*)(ws + OFF_WT);
    __hip_bfloat16* WoT = (__hip_bfloat16*)(ws + OFF_WO);
    __hip_bfloat16* QB  = (__hip_bfloat16*)(ws + OFF_QB);
    __hip_bfloat16* KB  = (__hip_bfloat16*)(ws + OFF_KB);
    __hip_bfloat16* VT  = (__hip_bfloat16*)(ws + OFF_VT);
    __hip_bfloat16* AOB = (__hip_bfloat16*)(ws + OFF_AO);
    float* mbias = (float*)(ws + OFF_MB);
    float* out   = (float*)d_out;

    hipLaunchKernelGGL(prep_kernel, dim3(4097), dim3(256), 0, stream,
                       x, Wq, Wk, Wv, Wo, am, XB, WT, WoT, mbias);
    hipLaunchKernelGGL(qkv_mfma_kernel, dim3(16, 32), dim3(256), 0, stream,
                       XB, WT, bq, bk, bv, fc, fs, QB, KB, VT);
    hipLaunchKernelGGL(attn_kernel, dim3(512), dim3(256), 0, stream,
                       QB, KB, VT, mbias, AOB);
    hipLaunchKernelGGL(out_mfma_kernel, dim3(8, 32), dim3(256), 0, stream,
                       AOB, WoT, bo, out);
}

// Round 14
// 131.842 us; speedup vs baseline: 1.1035x; 1.0721x over previous
//
#include <hip/hip_runtime.h>
#include <hip/hip_bf16.h>
#include <math.h>

// Problem constants: B=2, S=2048, D=1024, HQ=16, HKV=8, DK=DV=64
typedef __attribute__((ext_vector_type(8))) short bf16x8;   // 8 bf16 (4 VGPRs)
typedef __attribute__((ext_vector_type(4))) float f32x4;

// ws layout (byte offsets)
#define OFF_XB  0ull             // bf16 [4096][1024]   8 MB
#define OFF_WT  (8ull<<20)       // bf16 [2048][1024]   4 MB  ([Wq|Wk|Wv]^T)
#define OFF_WO  (12ull<<20)      // bf16 [1024][1024]   2 MB  (Wo^T)
#define OFF_QB  (14ull<<20)      // bf16 [2][16][2048][64]  8 MB (RoPE'd, scaled 1/8*log2e)
#define OFF_KB  (22ull<<20)      // bf16 [2][8][2048][64]   4 MB (RoPE'd)
#define OFF_VT  (26ull<<20)      // bf16 [2][8][64][2048]   4 MB (V^T)
#define OFF_AO  (30ull<<20)      // bf16 [4096][1024]   8 MB (attn out)
#define OFF_MB  (38ull<<20)      // f32  [2][2048] mask bias (0 / -1e30)

#define QSCALE 0.18033688056680276f   // 0.125 * log2(e): softmax in exp2 domain

__device__ inline unsigned pack_bf162(float a, float b) {
    __hip_bfloat162 t = __float22bfloat162_rn(make_float2(a, b));  // a -> low 16 bits
    return *(unsigned*)&t;
}

__device__ inline float exp2_fast(float x) {
    float r;
    asm("v_exp_f32 %0, %1" : "=v"(r) : "v"(x));
    return r;
}

__device__ inline void gload16(const void* g, void* l) {
    __builtin_amdgcn_global_load_lds(
        (const __attribute__((address_space(1))) void*)g,
        (__attribute__((address_space(3))) void*)l, 16, 0, 0);
}

// ---------------- prep: x->bf16, W transposes->bf16, mask canon ----------------
__launch_bounds__(256)
__global__ void prep_kernel(const float* __restrict__ x,
                            const float* __restrict__ Wq, const float* __restrict__ Wk,
                            const float* __restrict__ Wv, const float* __restrict__ Wo,
                            const void* __restrict__ mraw,
                            __hip_bfloat16* __restrict__ XB,
                            __hip_bfloat16* __restrict__ WT,
                            __hip_bfloat16* __restrict__ WoT,
                            float* __restrict__ mbias) {
    __shared__ float T[32][33];
    __shared__ int bad01, badf;
    const int tid = threadIdx.x;
    const int bid = blockIdx.x;
    if (bid < 1024) {                       // x -> bf16
        const int base = bid * 4096;
#pragma unroll
        for (int i = 0; i < 4; ++i) {
            const int e = base + (i * 256 + tid) * 4;
            const float4 v = *(const float4*)&x[e];
            uint2 pk;
            pk.x = pack_bf162(v.x, v.y);
            pk.y = pack_bf162(v.z, v.w);
            *(uint2*)&XB[e] = pk;
        }
    } else if (bid < 4096) {                // W transposes
        const float* src; int ldn, nbase; __hip_bfloat16* dst; int n0, k0;
        if (bid < 3072) {
            const int tb = bid - 1024;
            const int kt = tb >> 6, nt = tb & 63;
            n0 = nt * 32; k0 = kt * 32; dst = WT;
            if (n0 < 1024)      { src = Wq; ldn = 1024; nbase = n0; }
            else if (n0 < 1536) { src = Wk; ldn = 512;  nbase = n0 - 1024; }
            else                { src = Wv; ldn = 512;  nbase = n0 - 1536; }
        } else {
            const int tb = bid - 3072;
            const int kt = tb >> 5, nt = tb & 31;
            n0 = nt * 32; k0 = kt * 32; dst = WoT;
            src = Wo; ldn = 1024; nbase = n0;
        }
        const int c = tid & 31, r0 = tid >> 5;
#pragma unroll
        for (int i = 0; i < 4; ++i)
            T[r0 + 8 * i][c] = src[(size_t)(k0 + r0 + 8 * i) * ldn + nbase + c];
        __syncthreads();
#pragma unroll
        for (int i = 0; i < 4; ++i) {
            const int nn = r0 + 8 * i;
            dst[(size_t)(n0 + nn) * 1024 + k0 + c] = __float2bfloat16(T[c][nn]);
        }
    } else {                                // mask canonicalization
        if (tid == 0) { bad01 = 0; badf = 0; }
        __syncthreads();
        const unsigned* w = (const unsigned*)mraw;
#pragma unroll
        for (int i = 0; i < 4; ++i) {
            const unsigned v = w[tid * 4 + i];
            if (v > 1u) atomicAdd(&bad01, 1);
            if (v != 0u && v != 0x3F800000u) atomicAdd(&badf, 1);
        }
        __syncthreads();
        const int fmt = (bad01 == 0) ? 0 : ((badf == 0) ? 1 : 2); // 0=i32,1=f32,2=u8
        for (int i = tid; i < 4096; i += 256) {
            bool on;
            if (fmt == 2) on = (((const unsigned char*)mraw)[i] != 0);
            else          on = (w[i] != 0u);
            mbias[i] = on ? 0.f : -1e30f;
        }
    }
}

// ---------------- bf16 MFMA GEMM, double-buffered prefetch (attn-style) --------
#define QSTAGE(SEL, K0_) do {                                                    \
    _Pragma("unroll") for (int rnd_ = 0; rnd_ < 4; ++rnd_) {                     \
        const int off_ = rnd_ * 4096 + wid * 1024 + lane * 16;                   \
        const int row_ = off_ >> 7;                                              \
        const int ch_  = ((off_ >> 4) & 7) ^ (row_ & 7);                         \
        gload16((const char*)Ag + ((size_t)(n0 + row_) * 1024 + (K0_) + ch_ * 8) * 2, \
                Asm + (SEL) * 16384 + rnd_ * 4096 + wid * 1024);                 \
        gload16((const char*)Bg + ((size_t)(m0 + row_) * 1024 + (K0_) + ch_ * 8) * 2, \
                Bsm + (SEL) * 16384 + rnd_ * 4096 + wid * 1024);                 \
    }                                                                            \
} while (0)

__launch_bounds__(256)
__global__ void qkv_mfma_kernel(const __hip_bfloat16* __restrict__ XB,
                                const __hip_bfloat16* __restrict__ WT,
                                const float* __restrict__ bq, const float* __restrict__ bk,
                                const float* __restrict__ bv,
                                const float* __restrict__ fc, const float* __restrict__ fs,
                                __hip_bfloat16* __restrict__ QB,
                                __hip_bfloat16* __restrict__ KB,
                                __hip_bfloat16* __restrict__ VT) {
    __shared__ __attribute__((aligned(16))) char Asm[32768];  // 2 x WT rows [128][64k]
    __shared__ __attribute__((aligned(16))) char Bsm[32768];  // 2 x XB rows
    const int tid = threadIdx.x;
    const int lane = tid & 63, wid = tid >> 6;
    const int c = lane & 15, g = lane >> 4;
    const int n0 = blockIdx.x * 128, m0 = blockIdx.y * 128;
    const int wn = (wid >> 1) * 64, wm = (wid & 1) * 64;
    const __hip_bfloat16* Ag = WT;
    const __hip_bfloat16* Bg = XB;

    f32x4 acc[4][4];
#pragma unroll
    for (int ni = 0; ni < 4; ++ni)
#pragma unroll
        for (int mj = 0; mj < 4; ++mj) acc[ni][mj] = f32x4{0.f, 0.f, 0.f, 0.f};

    QSTAGE(0, 0);
    int cur = 0;
    for (int kt = 0; kt < 16; ++kt) {
        const int k0 = kt * 64;
        if (kt < 15) {
            QSTAGE(cur ^ 1, k0 + 64);
            asm volatile("s_waitcnt vmcnt(8)" ::: "memory");
        } else {
            asm volatile("s_waitcnt vmcnt(0)" ::: "memory");
        }
        __builtin_amdgcn_sched_barrier(0);
        __builtin_amdgcn_s_barrier();
        __builtin_amdgcn_sched_barrier(0);

        const char* Ac = Asm + cur * 16384;
        const char* Bc = Bsm + cur * 16384;
#pragma unroll
        for (int ks = 0; ks < 2; ++ks) {
            bf16x8 af[4], bfr[4];
#pragma unroll
            for (int t = 0; t < 4; ++t) {
                const int sl = ((g + 4 * ks) ^ (c & 7)) << 4;
                af[t]  = *(const bf16x8*)(Ac + (wn + 16 * t + c) * 128 + sl);
                bfr[t] = *(const bf16x8*)(Bc + (wm + 16 * t + c) * 128 + sl);
            }
#pragma unroll
            for (int ni = 0; ni < 4; ++ni)
#pragma unroll
                for (int mj = 0; mj < 4; ++mj)
                    acc[ni][mj] = __builtin_amdgcn_mfma_f32_16x16x32_bf16(
                        af[ni], bfr[mj], acc[ni][mj], 0, 0, 0);
        }
        __builtin_amdgcn_sched_barrier(0);
        __builtin_amdgcn_s_barrier();   // all waves done with buf[cur]
        __builtin_amdgcn_sched_barrier(0);
        cur ^= 1;
    }

#pragma unroll
    for (int ni = 0; ni < 4; ++ni) {
        const int nb = n0 + wn + 16 * ni + 4 * g;
        const float* bias; int nloc;
        if (nb < 1024)      { bias = bq; nloc = nb; }
        else if (nb < 1536) { bias = bk; nloc = nb - 1024; }
        else                { bias = bv; nloc = nb - 1536; }
        const float4 b4 = *(const float4*)&bias[nloc];
        const int h = nloc >> 6, dk = nb & 63;
#pragma unroll
        for (int mj = 0; mj < 4; ++mj) {
            const int tok = m0 + wm + 16 * mj + c;
            const int bb = tok >> 11, sp = tok & 2047;
            float v0 = acc[ni][mj][0] + b4.x;
            float v1 = acc[ni][mj][1] + b4.y;
            float v2 = acc[ni][mj][2] + b4.z;
            float v3 = acc[ni][mj][3] + b4.w;
            if (nb < 1536) {
                const int p = sp * 32 + (dk >> 1);
                const float c0 = fc[p], s0 = fs[p];
                const float c1 = fc[p + 1], s1 = fs[p + 1];
                float o0 = v0 * c0 - v1 * s0, o1 = v0 * s0 + v1 * c0;
                float o2 = v2 * c1 - v3 * s1, o3 = v2 * s1 + v3 * c1;
                uint2 pk;
                if (nb < 1024) {
                    o0 *= QSCALE; o1 *= QSCALE; o2 *= QSCALE; o3 *= QSCALE;
                    pk.x = pack_bf162(o0, o1); pk.y = pack_bf162(o2, o3);
                    *(uint2*)&QB[(size_t)((bb * 16 + h) * 2048 + sp) * 64 + dk] = pk;
                } else {
                    pk.x = pack_bf162(o0, o1); pk.y = pack_bf162(o2, o3);
                    *(uint2*)&KB[(size_t)((bb * 8 + h) * 2048 + sp) * 64 + dk] = pk;
                }
            } else {
                const size_t vb = (size_t)((bb * 8 + h) * 64 + dk) * 2048 + sp;
                VT[vb]          = __float2bfloat16(v0);
                VT[vb + 2048]   = __float2bfloat16(v1);
                VT[vb + 4096]   = __float2bfloat16(v2);
                VT[vb + 6144]   = __float2bfloat16(v3);
            }
        }
    }
}

// ---------------- out projection MFMA, double-buffered prefetch ----------------
__launch_bounds__(256)
__global__ void out_mfma_kernel(const __hip_bfloat16* __restrict__ AOB,
                                const __hip_bfloat16* __restrict__ WoT,
                                const float* __restrict__ bo,
                                float* __restrict__ out) {
    __shared__ __attribute__((aligned(16))) char Asm[32768];
    __shared__ __attribute__((aligned(16))) char Bsm[32768];
    const int tid = threadIdx.x;
    const int lane = tid & 63, wid = tid >> 6;
    const int c = lane & 15, g = lane >> 4;
    const int n0 = blockIdx.x * 128, m0 = blockIdx.y * 128;
    const int wn = (wid >> 1) * 64, wm = (wid & 1) * 64;
    const __hip_bfloat16* Ag = WoT;
    const __hip_bfloat16* Bg = AOB;

    f32x4 acc[4][4];
#pragma unroll
    for (int ni = 0; ni < 4; ++ni)
#pragma unroll
        for (int mj = 0; mj < 4; ++mj) acc[ni][mj] = f32x4{0.f, 0.f, 0.f, 0.f};

    QSTAGE(0, 0);
    int cur = 0;
    for (int kt = 0; kt < 16; ++kt) {
        const int k0 = kt * 64;
        if (kt < 15) {
            QSTAGE(cur ^ 1, k0 + 64);
            asm volatile("s_waitcnt vmcnt(8)" ::: "memory");
        } else {
            asm volatile("s_waitcnt vmcnt(0)" ::: "memory");
        }
        __builtin_amdgcn_sched_barrier(0);
        __builtin_amdgcn_s_barrier();
        __builtin_amdgcn_sched_barrier(0);

        const char* Ac = Asm + cur * 16384;
        const char* Bc = Bsm + cur * 16384;
#pragma unroll
        for (int ks = 0; ks < 2; ++ks) {
            bf16x8 af[4], bfr[4];
#pragma unroll
            for (int t = 0; t < 4; ++t) {
                const int sl = ((g + 4 * ks) ^ (c & 7)) << 4;
                af[t]  = *(const bf16x8*)(Ac + (wn + 16 * t + c) * 128 + sl);
                bfr[t] = *(const bf16x8*)(Bc + (wm + 16 * t + c) * 128 + sl);
            }
#pragma unroll
            for (int ni = 0; ni < 4; ++ni)
#pragma unroll
                for (int mj = 0; mj < 4; ++mj)
                    acc[ni][mj] = __builtin_amdgcn_mfma_f32_16x16x32_bf16(
                        af[ni], bfr[mj], acc[ni][mj], 0, 0, 0);
        }
        __builtin_amdgcn_sched_barrier(0);
        __builtin_amdgcn_s_barrier();
        __builtin_amdgcn_sched_barrier(0);
        cur ^= 1;
    }
#pragma unroll
    for (int ni = 0; ni < 4; ++ni) {
        const int nb = n0 + wn + 16 * ni + 4 * g;
        const float4 b4 = *(const float4*)&bo[nb];
#pragma unroll
        for (int mj = 0; mj < 4; ++mj) {
            const int tok = m0 + wm + 16 * mj + c;
            const f32x4 a = acc[ni][mj];
            const float4 st = make_float4(a[0] + b4.x, a[1] + b4.y,
                                          a[2] + b4.z, a[3] + b4.w);
            *(float4*)&out[(size_t)tok * 1024 + nb] = st;
        }
    }
}

// ---------------- flash attention: KVBLK=128, half the tiles/barriers ----------
// 512 blocks (XCD-swizzled), 4 waves, 32 q-rows/wave. K dbuf [128k][64d] (8-chunk
// XOR swz), V dbuf [64d][128k] (16-chunk XOR swz), single P [16q][128k]/wave.
// Per tile: STAGE(next) -> vmcnt(8) -> barrier -> QK(2 halves) -> per-rt
// {mask, max, defer, exp, P-write, PV(4 ks)} -> barrier. l via ones-MFMA.

#define STAGE128(SEL, K0_) do {                                                  \
    _Pragma("unroll") for (int rnd_ = 0; rnd_ < 4; ++rnd_) {                     \
        const int off_ = rnd_ * 4096 + wid * 1024 + lane * 16;                   \
        const int kr_ = off_ >> 7;                                               \
        const int kc_ = ((off_ >> 4) & 7) ^ (kr_ & 7);                           \
        gload16(Kh + (size_t)((K0_) + kr_) * 64 + kc_ * 8,                       \
                Ksm + (SEL) * 16384 + rnd_ * 4096 + wid * 1024);                 \
        const int vr_ = off_ >> 8;                                               \
        const int vc_ = ((off_ >> 4) & 15) ^ (vr_ & 15);                         \
        gload16(Vh + (size_t)vr_ * 2048 + (K0_) + vc_ * 8,                       \
                Vsm + (SEL) * 16384 + rnd_ * 4096 + wid * 1024);                 \
    }                                                                            \
} while (0)

__launch_bounds__(256, 2)
__global__ void attn_kernel(const __hip_bfloat16* __restrict__ QB,
                            const __hip_bfloat16* __restrict__ KB,
                            const __hip_bfloat16* __restrict__ VT,
                            const float* __restrict__ maskb,
                            __hip_bfloat16* __restrict__ AOB) {
    __shared__ __attribute__((aligned(16))) char Ksm[32768];   // 2 x [128 key][64 d]
    __shared__ __attribute__((aligned(16))) char Vsm[32768];   // 2 x [64 d][128 key]
    __shared__ char P_lds[4][4096];    // per wave: [16 q][128 key] bf16 (rt-shared)

    const int tid  = threadIdx.x;
    const int lane = tid & 63, wid = tid >> 6;
    const int c = lane & 15, g = lane >> 4;

    // XCD-aware swizzle: 512 blocks, 64 consecutive per XCD (2 KV heads/XCD L2)
    const int bid = blockIdx.x;
    const int o_  = (bid & 7) * 64 + (bid >> 3);
    const int qx = o_ & 15, h = (o_ >> 4) & 15, b = o_ >> 8;
    const int qb = qx * 128 + wid * 32;

    const __hip_bfloat16* Qh = QB + (size_t)(b * 16 + h)       * 2048 * 64;
    const __hip_bfloat16* Kh = KB + (size_t)(b * 8 + (h >> 1)) * 2048 * 64;
    const __hip_bfloat16* Vh = VT + (size_t)(b * 8 + (h >> 1)) * 64 * 2048;
    const float* mb = maskb + b * 2048;

    STAGE128(0, 0);

    bf16x8 bq[2][2];
#pragma unroll
    for (int rt = 0; rt < 2; ++rt)
#pragma unroll
        for (int ks = 0; ks < 2; ++ks)
            bq[rt][ks] = *(const bf16x8*)&Qh[(size_t)(qb + 16 * rt + c) * 64
                                             + 32 * ks + 8 * g];
    __syncthreads();   // stage0 + bq complete

    const short oneb = (short)0x3F80;
    const bf16x8 ones = {oneb, oneb, oneb, oneb, oneb, oneb, oneb, oneb};

    f32x4 o[2][4];
    f32x4 lacc[2];
#pragma unroll
    for (int rt = 0; rt < 2; ++rt) {
        lacc[rt] = f32x4{0.f, 0.f, 0.f, 0.f};
#pragma unroll
        for (int mt = 0; mt < 4; ++mt) o[rt][mt] = f32x4{0.f, 0.f, 0.f, 0.f};
    }
    float m_[2] = {-INFINITY, -INFINITY};

    char* Pr = &P_lds[wid][0] + c * 256;
    const int swz = (c & 7) << 4;

    int cur = 0;
    for (int kt = 0; kt < 16; ++kt) {
        const int k0 = kt * 128;
        if (kt < 15) {
            STAGE128(cur ^ 1, k0 + 128);
            asm volatile("s_waitcnt vmcnt(8)" ::: "memory");
        } else {
            asm volatile("s_waitcnt vmcnt(0)" ::: "memory");
        }
        __builtin_amdgcn_sched_barrier(0);
        __builtin_amdgcn_s_barrier();
        __builtin_amdgcn_sched_barrier(0);

        const char* Kc = Ksm + cur * 16384;
        const char* Vc = Vsm + cur * 16384;

        // mask-bias loads issued early (L2-hot; latency hides under QK MFMAs)
        const bool needb = (k0 + 127 > qb);
        f32x4 bv4[8];
        if (needb) {
#pragma unroll
            for (int mt = 0; mt < 8; ++mt)
                bv4[mt] = *(const f32x4*)&mb[k0 + 16 * mt + 4 * g];
        }

        // QK over 128 keys in two 64-key halves (ak regs reused across halves)
        f32x4 st[2][8];
        __builtin_amdgcn_s_setprio(1);
#pragma unroll
        for (int hf = 0; hf < 2; ++hf) {
            bf16x8 ak[4][2];
#pragma unroll
            for (int mt = 0; mt < 4; ++mt)
#pragma unroll
                for (int ks = 0; ks < 2; ++ks)
                    ak[mt][ks] = *(const bf16x8*)(Kc + (64 * hf + 16 * mt + c) * 128
                                                  + (((g + 4 * ks) ^ (c & 7)) << 4));
#pragma unroll
            for (int rt = 0; rt < 2; ++rt)
#pragma unroll
                for (int mt = 0; mt < 4; ++mt) {
                    f32x4 z = f32x4{0.f, 0.f, 0.f, 0.f};
                    z = __builtin_amdgcn_mfma_f32_16x16x32_bf16(ak[mt][0], bq[rt][0], z, 0, 0, 0);
                    z = __builtin_amdgcn_mfma_f32_16x16x32_bf16(ak[mt][1], bq[rt][1], z, 0, 0, 0);
                    st[rt][4 * hf + mt] = z;
                }
        }
        __builtin_amdgcn_s_setprio(0);

        // ---- per rt: mask, softmax, P-write, P-read + PV ----
#pragma unroll
        for (int rt = 0; rt < 2; ++rt) {
            const int qw = qb + 16 * rt;
            if (k0 + 127 <= qw) {
                // fully causal: no mask work
            } else if (k0 > qw + 15) {             // fully future: vector bias add
#pragma unroll
                for (int mt = 0; mt < 8; ++mt)
                    st[rt][mt] = st[rt][mt] + bv4[mt];
            } else {                               // mixed (diagonal) tile
                const int qg = qw + c;
#pragma unroll
                for (int mt = 0; mt < 8; ++mt)
#pragma unroll
                    for (int r = 0; r < 4; ++r) {
                        const int kg = k0 + 16 * mt + 4 * g + r;
                        st[rt][mt][r] += (kg <= qg) ? 0.f : bv4[mt][r];
                    }
            }
            // vector tree max over 8 f32x4
            const f32x4 a0 = __builtin_elementwise_max(st[rt][0], st[rt][1]);
            const f32x4 a1 = __builtin_elementwise_max(st[rt][2], st[rt][3]);
            const f32x4 a2 = __builtin_elementwise_max(st[rt][4], st[rt][5]);
            const f32x4 a3 = __builtin_elementwise_max(st[rt][6], st[rt][7]);
            const f32x4 b0 = __builtin_elementwise_max(a0, a1);
            const f32x4 b1 = __builtin_elementwise_max(a2, a3);
            const f32x4 mv = __builtin_elementwise_max(b0, b1);
            float pmax = fmaxf(fmaxf(mv[0], mv[1]), fmaxf(mv[2], mv[3]));
            pmax = fmaxf(pmax, __shfl_xor(pmax, 16));
            pmax = fmaxf(pmax, __shfl_xor(pmax, 32));
            if (!__all(pmax <= m_[rt] + 11.5f)) {  // defer-rescale (T13)
                const float mn = fmaxf(m_[rt], pmax);
                const float alpha = exp2_fast(m_[rt] - mn);
                m_[rt] = mn;
                lacc[rt][0] *= alpha;              // only reg0 of lacc is read
#pragma unroll
                for (int mt = 0; mt < 4; ++mt) o[rt][mt] *= alpha;
            }
            const float mneg = m_[rt];
            const f32x4 m4 = {mneg, mneg, mneg, mneg};
#pragma unroll
            for (int mt = 0; mt < 8; ++mt) {
                const f32x4 e = st[rt][mt] - m4;
#pragma unroll
                for (int r = 0; r < 4; ++r)
                    st[rt][mt][r] = exp2_fast(e[r]);
            }

            // P -> LDS [q=c][128 key], swizzled 8B slots (single buffer per wave;
            // same-wave DS ordering makes the rt1 overwrite safe after rt0 reads)
#pragma unroll
            for (int mt = 0; mt < 8; ++mt) {
                const unsigned w0 = pack_bf162(st[rt][mt][0], st[rt][mt][1]);
                const unsigned w1 = pack_bf162(st[rt][mt][2], st[rt][mt][3]);
                *(unsigned long long*)(Pr + ((32 * mt + 8 * g) ^ swz)) =
                    (unsigned long long)w0 | ((unsigned long long)w1 << 32);
            }

            // PV over 4 ks-blocks of 32 keys; V frags reloaded per ks from LDS
            __builtin_amdgcn_s_setprio(1);
#pragma unroll
            for (int ks = 0; ks < 4; ++ks) {
                const bf16x8 pb = *(const bf16x8*)(Pr + ((64 * ks + 16 * g) ^ swz));
                bf16x8 av[4];
#pragma unroll
                for (int mt = 0; mt < 4; ++mt)
                    av[mt] = *(const bf16x8*)(Vc + (16 * mt + c) * 256
                                              + (((4 * ks + g) ^ (c & 15)) << 4));
#pragma unroll
                for (int mt = 0; mt < 4; ++mt)
                    o[rt][mt] = __builtin_amdgcn_mfma_f32_16x16x32_bf16(av[mt], pb, o[rt][mt], 0, 0, 0);
                lacc[rt] = __builtin_amdgcn_mfma_f32_16x16x32_bf16(ones, pb, lacc[rt], 0, 0, 0);
            }
            __builtin_amdgcn_s_setprio(0);
        }

        __builtin_amdgcn_sched_barrier(0);
        __builtin_amdgcn_s_barrier();   // all waves done reading buf[cur]
        __builtin_amdgcn_sched_barrier(0);
        cur ^= 1;
    }

#pragma unroll
    for (int rt = 0; rt < 2; ++rt) {
        const float inv = 1.f / lacc[rt][0];
        const size_t tok = (size_t)(b * 2048 + qb + 16 * rt + c);
#pragma unroll
        for (int mt = 0; mt < 4; ++mt) {
            uint2 pk;
            pk.x = pack_bf162(o[rt][mt][0] * inv, o[rt][mt][1] * inv);
            pk.y = pack_bf162(o[rt][mt][2] * inv, o[rt][mt][3] * inv);
            *(uint2*)&AOB[tok * 1024 + h * 64 + 16 * mt + 4 * g] = pk;
        }
    }
}

extern "C" void kernel_launch(void* const* d_in, const int* in_sizes, int n_in,
                              void* d_out, int out_size, void* d_ws, size_t ws_size,
                              hipStream_t stream) {
    const float* x  = (const float*)d_in[0];
    const float* Wq = (const float*)d_in[1];
    const float* bq = (const float*)d_in[2];
    const float* Wk = (const float*)d_in[3];
    const float* bk = (const float*)d_in[4];
    const float* Wv = (const float*)d_in[5];
    const float* bv = (const float*)d_in[6];
    const float* Wo = (const float*)d_in[7];
    const float* bo = (const float*)d_in[8];
    const float* fc = (const float*)d_in[9];
    const float* fs = (const float*)d_in[10];
    const void*  am = d_in[11];

    char* ws = (char*)d_ws;
    __hip_bfloat16* XB  = (__hip_bfloat16*)(ws + OFF_XB);
    __hip_bfloat16* WT  = (__hip_bfloat16*)(ws + OFF_WT);
    __hip_bfloat16* WoT = (__hip_bfloat16*)(ws + OFF_WO);
    __hip_bfloat16* QB  = (__hip_bfloat16*)(ws + OFF_QB);
    __hip_bfloat16* KB  = (__hip_bfloat16*)(ws + OFF_KB);
    __hip_bfloat16* VT  = (__hip_bfloat16*)(ws + OFF_VT);
    __hip_bfloat16* AOB = (__hip_bfloat16*)(ws + OFF_AO);
    float* mbias = (float*)(ws + OFF_MB);
    float* out   = (float*)d_out;

    hipLaunchKernelGGL(prep_kernel, dim3(4097), dim3(256), 0, stream,
                       x, Wq, Wk, Wv, Wo, am, XB, WT, WoT, mbias);
    hipLaunchKernelGGL(qkv_mfma_kernel, dim3(16, 32), dim3(256), 0, stream,
                       XB, WT, bq, bk, bv, fc, fs, QB, KB, VT);
    hipLaunchKernelGGL(attn_kernel, dim3(512), dim3(256), 0, stream,
                       QB, KB, VT, mbias, AOB);
    hipLaunchKernelGGL(out_mfma_kernel, dim3(8, 32), dim3(256), 0, stream,
                       AOB, WoT, bo, out);
}